// Round 2
// baseline (1796.427 us; speedup 1.0000x reference)
//
#include <hip/hip_runtime.h>

typedef unsigned short u16;
typedef unsigned int   u32;

#define NN 16384
#define BN 524288      /* B*N = 32*16384 */
#define LN_EPS 1e-5f

// ---------------- helpers ----------------
__device__ __forceinline__ float bf2f(u16 h){
  union { u32 u; float f; } c; c.u = ((u32)h) << 16; return c.f;
}
__device__ __forceinline__ u16 f2bf(float f){
  union { float f; u32 u; } c; c.f = f;
  u32 r = (c.u + 0x7fffu + ((c.u >> 16) & 1u)) >> 16;   // RNE
  return (u16)r;
}
__device__ __forceinline__ u32 pack2(float a, float b){
  return (u32)f2bf(a) | ((u32)f2bf(b) << 16);
}
__device__ __forceinline__ void unpack8(uint4 v, float* o){
  o[0]=bf2f((u16)(v.x&0xffffu)); o[1]=bf2f((u16)(v.x>>16));
  o[2]=bf2f((u16)(v.y&0xffffu)); o[3]=bf2f((u16)(v.y>>16));
  o[4]=bf2f((u16)(v.z&0xffffu)); o[5]=bf2f((u16)(v.z>>16));
  o[6]=bf2f((u16)(v.w&0xffffu)); o[7]=bf2f((u16)(v.w>>16));
}

// ---------------- fp32 weight arena offsets (floats) ----------------
enum {
  O_LNING=0, O_LNINB=64, O_LNSG=128, O_LNSB=192, O_LNMG=256, O_LNMB=320,
  O_WQ=384, O_WK=4480, O_WV=8576,
  O_WIH=12672, O_WHH=24960, O_BIH=37248, O_BHH=37440,
  O_MLPW1=37632, O_MLPB1=45824, O_MLPW2=45952, O_MLPB2=54144,
  O_PAW=54208, O_PAB=54336,
  O_PEG=54400, O_PEB=54464, O_PEW1=54528, O_PEB1=62720, O_PEW2=62848, O_PEB2=71040,
  W_TOTAL=71104
};
__device__ const int g_woff[25] = {O_LNING,O_LNINB,O_LNSG,O_LNSB,O_LNMG,O_LNMB,
  O_WQ,O_WK,O_WV,O_WIH,O_WHH,O_BIH,O_BHH,O_MLPW1,O_MLPB1,O_MLPW2,O_MLPB2,
  O_PAW,O_PAB,O_PEG,O_PEB,O_PEW1,O_PEB1,O_PEW2,O_PEB2};
__device__ const int g_wsz[25]  = {64,64,64,64,64,64,4096,4096,4096,12288,12288,
  192,192,8192,128,8192,64,128,64,64,64,8192,128,8192,64};

struct WP { const void* p[25]; };

// ---------------- kernel: detect input dtype ----------------
// If inputs are bf16: even-indexed u16s are genuine ~N(0,1) bf16 values
// (exponent field in a sane range). If fp32: even-indexed u16s are low-order
// mantissa bits -> uniformly random exponent field (~18% sane). Vote.
__global__ void kdetect_kernel(const u16* __restrict__ inp, int* __restrict__ flag){
  if (threadIdx.x == 0 && blockIdx.x == 0){
    int votes = 0;
    for (int i = 0; i < 64; i++){
      u16 h = inp[2*i];
      int e = (h >> 7) & 0xff;
      int m = h & 0x7f;
      if ((e == 0 && m == 0) || (e >= 100 && e <= 144)) votes++;
    }
    flag[0] = (votes >= 48) ? 1 : 0;   // 1 = bf16, 0 = fp32
  }
}

// ---------------- kernel: weight convert (->fp32 arena) + state init ----------------
__global__ __launch_bounds__(256) void kw_kernel(WP wp, float* __restrict__ w,
                                                 float* __restrict__ state,
                                                 const void* __restrict__ slots,
                                                 const int* __restrict__ flag){
  int isbf = flag[0];
  int blk = blockIdx.x;
  if (blk < 25){
    const u16*   s16 = (const u16*)wp.p[blk];
    const float* s32 = (const float*)wp.p[blk];
    int off = g_woff[blk], sz = g_wsz[blk];
    for (int i = threadIdx.x; i < sz; i += 256)
      w[off + i] = isbf ? bf2f(s16[i]) : s32[i];
  } else {
    const u16*   s16 = (const u16*)slots;
    const float* s32 = (const float*)slots;
    for (int i = threadIdx.x; i < 512; i += 256){
      float sv = isbf ? bf2f(s16[i]) : s32[i];
      for (int b = 0; b < 32; b++) state[b*512 + i] = sv;
    }
  }
}

// ---------------- kernel: input LN + k = x@Wk, v = x@Wv  (thread per row) ----------------
__global__ __launch_bounds__(256) void k0a_kernel(const void* __restrict__ inpv,
                                                  const float* __restrict__ w,
                                                  u16* __restrict__ kbuf,
                                                  u16* __restrict__ vbuf,
                                                  const int* __restrict__ flag){
  int isbf = flag[0];
  size_t row = (size_t)blockIdx.x*256 + threadIdx.x;   // [0, BN)
  float x[64];
  if (isbf){
    const u32* up = (const u32*)((const u16*)inpv + row*66);  // row*132 bytes, 4-aligned
#pragma unroll
    for (int c = 0; c < 32; c++){
      u32 v = up[c];
      x[2*c]   = bf2f((u16)(v & 0xffffu));
      x[2*c+1] = bf2f((u16)(v >> 16));
    }
  } else {
    const float2* fp = (const float2*)((const float*)inpv + row*66); // row*264 bytes, 8-aligned
#pragma unroll
    for (int c = 0; c < 32; c++){
      float2 v = fp[c];
      x[2*c] = v.x; x[2*c+1] = v.y;
    }
  }
  // layernorm(feats, ln_in_g, ln_in_b)
  float mu = 0.f;
#pragma unroll
  for (int i = 0; i < 64; i++) mu += x[i];
  mu *= (1.f/64.f);
  float va = 0.f;
#pragma unroll
  for (int i = 0; i < 64; i++){ x[i] -= mu; va += x[i]*x[i]; }
  va *= (1.f/64.f);
  float rs = rsqrtf(va + LN_EPS);
#pragma unroll
  for (int i = 0; i < 64; i++) x[i] = x[i]*rs*w[O_LNING+i] + w[O_LNINB+i];

  u32* kout = (u32*)(kbuf + row*64);
  u32* vout = (u32*)(vbuf + row*64);
  for (int d2 = 0; d2 < 32; d2++){      // rolled: weights via uniform scalar loads
    float a0=0.f, a1=0.f, b0=0.f, b1=0.f;
#pragma unroll
    for (int i = 0; i < 64; i++){
      float xi = x[i];
      a0 += xi * w[O_WK + i*64 + 2*d2];
      a1 += xi * w[O_WK + i*64 + 2*d2 + 1];
      b0 += xi * w[O_WV + i*64 + 2*d2];
      b1 += xi * w[O_WV + i*64 + 2*d2 + 1];
    }
    kout[d2] = pack2(a0, a1);
    vout[d2] = pack2(b0, b1);
  }
}

// ---------------- kernel: positional-MLP, in place, over 2*BN virtual rows ----------------
__global__ __launch_bounds__(256) void k0b_kernel(const void* __restrict__ inpv,
                                                  const float* __restrict__ w,
                                                  u16* __restrict__ kbuf,
                                                  u16* __restrict__ vbuf,
                                                  const int* __restrict__ flag){
  int isbf = flag[0];
  size_t r = (size_t)blockIdx.x*256 + threadIdx.x;     // [0, 2*BN)
  size_t row = (r < (size_t)BN) ? r : r - (size_t)BN;  // uniform per block
  u16* base = (r < (size_t)BN) ? kbuf : vbuf;

  float g0, g1;
  if (isbf){
    u32 gv = *(const u32*)((const u16*)inpv + row*66 + 64);
    g0 = bf2f((u16)(gv & 0xffffu)); g1 = bf2f((u16)(gv >> 16));
  } else {
    float2 gv = *(const float2*)((const float*)inpv + row*66 + 64);
    g0 = gv.x; g1 = gv.y;
  }

  float tv[64];
  const uint4* rp = (const uint4*)(base + row*64);
#pragma unroll
  for (int c = 0; c < 8; c++){ uint4 q4 = rp[c]; unpack8(q4, &tv[c*8]); }

  // x + grid_proj
#pragma unroll
  for (int i = 0; i < 64; i++)
    tv[i] += g0*w[O_PAW+i] + g1*w[O_PAW+64+i] + w[O_PAB+i];

  // layernorm(.., pe_g, pe_b)
  float mu = 0.f;
#pragma unroll
  for (int i = 0; i < 64; i++) mu += tv[i];
  mu *= (1.f/64.f);
  float va = 0.f;
#pragma unroll
  for (int i = 0; i < 64; i++){ tv[i] -= mu; va += tv[i]*tv[i]; }
  va *= (1.f/64.f);
  float rs = rsqrtf(va + LN_EPS);
#pragma unroll
  for (int i = 0; i < 64; i++) tv[i] = tv[i]*rs*w[O_PEG+i] + w[O_PEB+i];

  float out[64];
#pragma unroll
  for (int d = 0; d < 64; d++) out[d] = w[O_PEB2+d];

  for (int j = 0; j < 128; j++){        // rolled: only uniform weight indices depend on j
    float h = w[O_PEB1+j];
#pragma unroll
    for (int i = 0; i < 64; i++) h += tv[i] * w[O_PEW1 + i*128 + j];
    h = fmaxf(h, 0.f);
#pragma unroll
    for (int d = 0; d < 64; d++) out[d] += h * w[O_PEW2 + j*64 + d];
  }

  u32* op = (u32*)(base + row*64);
#pragma unroll
  for (int d2 = 0; d2 < 32; d2++) op[d2] = pack2(out[2*d2], out[2*d2+1]);
}

// ---------------- kernel: q = LN(state)@Wq ; zero accumulators (wave per slot-row) ----------------
__global__ __launch_bounds__(64) void b1_kernel(const float* __restrict__ w,
                                                const float* __restrict__ state,
                                                float* __restrict__ qbuf,
                                                float* __restrict__ upd,
                                                float* __restrict__ sums){
  int rrow = blockIdx.x;          // [0,256) = b*8+s
  int lane = threadIdx.x;
  float xv = state[rrow*64 + lane];
  float sum = xv;
#pragma unroll
  for (int off = 32; off; off >>= 1) sum += __shfl_xor(sum, off, 64);
  float mu = sum * (1.f/64.f);
  float xc = xv - mu;
  float ss = xc*xc;
#pragma unroll
  for (int off = 32; off; off >>= 1) ss += __shfl_xor(ss, off, 64);
  float rs = rsqrtf(ss*(1.f/64.f) + LN_EPS);
  float xln = xc*rs*w[O_LNSG+lane] + w[O_LNSB+lane];
  float acc = 0.f;
#pragma unroll
  for (int i = 0; i < 64; i++){
    float xi = __shfl(xln, i, 64);
    acc += xi * w[O_WQ + i*64 + lane];
  }
  qbuf[rrow*64 + lane] = acc;
  upd[rrow*64 + lane]  = 0.f;
  if (lane == 0) sums[rrow] = 0.f;
}

// ---------------- kernel: attention pass (512 n per block) ----------------
__global__ __launch_bounds__(512) void b2_kernel(const u16* __restrict__ kbuf,
                                                 const u16* __restrict__ vbuf,
                                                 const float* __restrict__ qbuf,
                                                 float* __restrict__ upd,
                                                 float* __restrict__ sums){
  __shared__ float qs[512];
  __shared__ float pmat[8*512];
  int t  = threadIdx.x;
  int b  = blockIdx.x >> 5;
  int n0 = (blockIdx.x & 31) << 9;

  qs[t] = qbuf[b*512 + t];
  __syncthreads();

  // phase A: thread-per-n logits + softmax over S=8
  size_t n = (size_t)b*NN + n0 + t;
  float kreg[64];
  const uint4* kp = (const uint4*)(kbuf + n*64);
#pragma unroll
  for (int c = 0; c < 8; c++){ uint4 v = kp[c]; unpack8(v, &kreg[c*8]); }

  float l[8];
#pragma unroll
  for (int s = 0; s < 8; s++){
    float a = 0.f;
#pragma unroll
    for (int i = 0; i < 64; i++) a += kreg[i]*qs[s*64+i];
    l[s] = a * 0.125f;                      // D^-0.5
  }
  float m = l[0];
#pragma unroll
  for (int s = 1; s < 8; s++) m = fmaxf(m, l[s]);
  float esum = 0.f;
#pragma unroll
  for (int s = 0; s < 8; s++){ l[s] = __expf(l[s]-m); esum += l[s]; }
  float inv = 1.f/esum;
#pragma unroll
  for (int s = 0; s < 8; s++) pmat[s*512 + t] = l[s]*inv + 1e-8f;
  __syncthreads();

  // phase B: wave w handles slot s=w; lane = d
  int s = t >> 6, d = t & 63;
  float part = 0.f;
#pragma unroll
  for (int c = 0; c < 8; c++) part += pmat[s*512 + c*64 + d];
#pragma unroll
  for (int off = 32; off; off >>= 1) part += __shfl_xor(part, off, 64);
  if (d == 0) atomicAdd(&sums[b*8 + s], part);

  const u16* vp = vbuf + ((size_t)b*NN + n0)*64 + d;
  float acc = 0.f;
#pragma unroll 8
  for (int j = 0; j < 512; j++)
    acc += pmat[s*512 + j] * bf2f(vp[(size_t)j*64]);
  atomicAdd(&upd[b*512 + s*64 + d], acc);
}

// ---------------- kernel: GRU + residual MLP state update (block per batch) ----------------
__global__ __launch_bounds__(256) void b3_kernel(const float* __restrict__ w,
                                                 float* __restrict__ state,
                                                 const float* __restrict__ upd,
                                                 const float* __restrict__ sums){
  __shared__ float uL[512], pL[512], gxL[1536], ghL[1536], hL[512], hidL[1024];
  __shared__ float muL[8], rsL[8];
  int t = threadIdx.x, b = blockIdx.x;

#pragma unroll
  for (int e = 0; e < 2; e++){
    int idx = t + 256*e; int s = idx >> 6;
    uL[idx] = upd[b*512 + idx] / sums[b*8 + s];   // fold attn-sum normalization
    pL[idx] = state[b*512 + idx];
  }
  __syncthreads();

  for (int e = 0; e < 6; e++){
    int idx = t + 256*e; int s = idx/192, j = idx - s*192;
    float ax = w[O_BIH + j], ah = w[O_BHH + j];
    for (int d = 0; d < 64; d++){
      ax += uL[s*64+d] * w[O_WIH + d*192 + j];
      ah += pL[s*64+d] * w[O_WHH + d*192 + j];
    }
    gxL[idx] = ax; ghL[idx] = ah;
  }
  __syncthreads();

#pragma unroll
  for (int e = 0; e < 2; e++){
    int idx = t + 256*e; int s = idx >> 6, d = idx & 63;
    float xr = gxL[s*192+d],     hr = ghL[s*192+d];
    float xz = gxL[s*192+64+d],  hz = ghL[s*192+64+d];
    float xn = gxL[s*192+128+d], hn = ghL[s*192+128+d];
    float r = 1.f/(1.f + expf(-(xr+hr)));
    float z = 1.f/(1.f + expf(-(xz+hz)));
    float nv = tanhf(xn + r*hn);
    hL[idx] = (1.f - z)*nv + z*pL[idx];
  }
  __syncthreads();

  if (t < 8){
    float mu = 0.f;
    for (int d = 0; d < 64; d++) mu += hL[t*64+d];
    mu *= (1.f/64.f);
    float va = 0.f;
    for (int d = 0; d < 64; d++){ float c = hL[t*64+d]-mu; va += c*c; }
    muL[t] = mu; rsL[t] = rsqrtf(va*(1.f/64.f) + LN_EPS);
  }
  __syncthreads();

  for (int e = 0; e < 4; e++){
    int idx = t + 256*e; int s = idx >> 7, j = idx & 127;
    float a = w[O_MLPB1 + j];
    for (int d = 0; d < 64; d++){
      float xln = (hL[s*64+d]-muL[s])*rsL[s]*w[O_LNMG+d] + w[O_LNMB+d];
      a += xln * w[O_MLPW1 + d*128 + j];
    }
    hidL[idx] = fmaxf(a, 0.f);
  }
  __syncthreads();

#pragma unroll
  for (int e = 0; e < 2; e++){
    int idx = t + 256*e; int s = idx >> 6, d = idx & 63;
    float o = w[O_MLPB2 + d];
    for (int j = 0; j < 128; j++) o += hidL[s*128+j] * w[O_MLPW2 + j*64 + d];
    state[b*512 + idx] = hL[idx] + o;
  }
}

// ---------------- kernel: state (fp32) -> out (bf16 or fp32 per flag) ----------------
__global__ __launch_bounds__(256) void kout_kernel(const float* __restrict__ state,
                                                   void* __restrict__ out,
                                                   const int* __restrict__ flag){
  int i = blockIdx.x*256 + threadIdx.x;
  if (flag[0]) ((u16*)out)[i] = f2bf(state[i]);
  else         ((float*)out)[i] = state[i];
}

// ---------------- launch ----------------
extern "C" void kernel_launch(void* const* d_in, const int* in_sizes, int n_in,
                              void* d_out, int out_size, void* d_ws, size_t ws_size,
                              hipStream_t stream){
  const void* inp   = d_in[0];
  const void* slots = d_in[1];
  WP wp;
  for (int i = 0; i < 25; i++) wp.p[i] = d_in[2+i];

  u16*   kbuf  = (u16*)d_ws;                         // BN*64 bf16 (k -> k_pos in place)
  u16*   vbuf  = kbuf + (size_t)BN*64;               // BN*64 bf16 (v -> v_pos in place)
  float* w     = (float*)(vbuf + (size_t)BN*64);     // fp32 weight arena
  float* state = w + W_TOTAL;                        // 32*8*64
  float* qbuf  = state + 16384;
  float* upd   = qbuf + 16384;
  float* sums  = upd + 16384;                        // 256
  int*   flag  = (int*)(sums + 256);

  kdetect_kernel<<<1, 64, 0, stream>>>((const u16*)inp, flag);
  kw_kernel<<<26, 256, 0, stream>>>(wp, w, state, slots, flag);
  k0a_kernel<<<2048, 256, 0, stream>>>(inp, w, kbuf, vbuf, flag);
  k0b_kernel<<<4096, 256, 0, stream>>>(inp, w, kbuf, vbuf, flag);
  for (int it = 0; it < 3; it++){
    b1_kernel<<<256, 64, 0, stream>>>(w, state, qbuf, upd, sums);
    b2_kernel<<<1024, 512, 0, stream>>>(kbuf, vbuf, qbuf, upd, sums);
    b3_kernel<<<32, 256, 0, stream>>>(w, state, upd, sums);
  }
  kout_kernel<<<64, 256, 0, stream>>>(state, d_out, flag);
}

// Round 3
// 746.592 us; speedup vs baseline: 2.4062x; 2.4062x over previous
//
#include <hip/hip_runtime.h>

typedef unsigned short u16;
typedef unsigned int   u32;

#define NN 16384
#define BN 524288      /* B*N = 32*16384 */
#define LN_EPS 1e-5f

typedef __attribute__((ext_vector_type(8))) short bf16x8;
typedef __attribute__((ext_vector_type(4))) float f32x4;
#define MFMA(a,b,c) __builtin_amdgcn_mfma_f32_16x16x32_bf16(a,b,c,0,0,0)

// ---------------- helpers ----------------
__device__ __forceinline__ float bf2f(u16 h){
  union { u32 u; float f; } c; c.u = ((u32)h) << 16; return c.f;
}
__device__ __forceinline__ u16 f2bf(float f){
  union { float f; u32 u; } c; c.f = f;
  u32 r = (c.u + 0x7fffu + ((c.u >> 16) & 1u)) >> 16;   // RNE
  return (u16)r;
}
__device__ __forceinline__ u32 pack2(float a, float b){
  return (u32)f2bf(a) | ((u32)f2bf(b) << 16);
}
__device__ __forceinline__ void unpack8(uint4 v, float* o){
  o[0]=bf2f((u16)(v.x&0xffffu)); o[1]=bf2f((u16)(v.x>>16));
  o[2]=bf2f((u16)(v.y&0xffffu)); o[3]=bf2f((u16)(v.y>>16));
  o[4]=bf2f((u16)(v.z&0xffffu)); o[5]=bf2f((u16)(v.z>>16));
  o[6]=bf2f((u16)(v.w&0xffffu)); o[7]=bf2f((u16)(v.w>>16));
}
__device__ __forceinline__ float ldin(const void* p, int i, int isbf){
  return isbf ? bf2f(((const u16*)p)[i]) : ((const float*)p)[i];
}

// ---------------- fp32 weight arena offsets (floats) ----------------
enum {
  O_LNING=0, O_LNINB=64, O_LNSG=128, O_LNSB=192, O_LNMG=256, O_LNMB=320,
  O_WQ=384, O_WK=4480, O_WV=8576,
  O_WIH=12672, O_WHH=24960, O_BIH=37248, O_BHH=37440,
  O_MLPW1=37632, O_MLPB1=45824, O_MLPW2=45952, O_MLPB2=54144,
  O_PAW=54208, O_PAB=54336,
  O_PEG=54400, O_PEB=54464, O_PEW1=54528, O_PEB1=62720, O_PEW2=62848, O_PEB2=71040,
  W_TOTAL=71104
};
__device__ const int g_woff[25] = {O_LNING,O_LNINB,O_LNSG,O_LNSB,O_LNMG,O_LNMB,
  O_WQ,O_WK,O_WV,O_WIH,O_WHH,O_BIH,O_BHH,O_MLPW1,O_MLPB1,O_MLPW2,O_MLPB2,
  O_PAW,O_PAB,O_PEG,O_PEB,O_PEW1,O_PEB1,O_PEW2,O_PEB2};
__device__ const int g_wsz[25]  = {64,64,64,64,64,64,4096,4096,4096,12288,12288,
  192,192,8192,128,8192,64,128,64,64,64,8192,128,8192,64};

struct WP { const void* p[25]; };

// ---------------- kernel: detect input dtype ----------------
__global__ void kdetect_kernel(const u16* __restrict__ inp, int* __restrict__ flag){
  if (threadIdx.x == 0 && blockIdx.x == 0){
    int votes = 0;
    for (int i = 0; i < 64; i++){
      u16 h = inp[2*i];
      int e = (h >> 7) & 0xff;
      int m = h & 0x7f;
      if ((e == 0 && m == 0) || (e >= 100 && e <= 144)) votes++;
    }
    flag[0] = (votes >= 48) ? 1 : 0;   // 1 = bf16, 0 = fp32
  }
}

// ---------------- kernel: weight convert (->fp32 arena) + state init ----------------
__global__ __launch_bounds__(256) void kw_kernel(WP wp, float* __restrict__ w,
                                                 float* __restrict__ state,
                                                 const void* __restrict__ slots,
                                                 const int* __restrict__ flag){
  int isbf = flag[0];
  int blk = blockIdx.x;
  if (blk < 25){
    const void* src = wp.p[blk];
    int off = g_woff[blk], sz = g_wsz[blk];
    for (int i = threadIdx.x; i < sz; i += 256)
      w[off + i] = ldin(src, i, isbf);
  } else {
    for (int i = threadIdx.x; i < 512; i += 256){
      float sv = ldin(slots, i, isbf);
      for (int b = 0; b < 32; b++) state[b*512 + i] = sv;
    }
  }
}

// ---------------- kernel: pack B-fragment buffers (bf16, MFMA B-layout) ----------------
// B-frag for mfma_f32_16x16x32_bf16: lane holds B[k][n] with n = ntile*16 + (lane&15),
// k = kstep*32 + (lane>>4)*8 + j (j=0..7). Stored frag-major: fb[frag*512 + lane*8 + j].
__global__ __launch_bounds__(256) void kpack_kernel(WP wp, u16* __restrict__ fkv,
                                                    u16* __restrict__ f1,
                                                    u16* __restrict__ f2,
                                                    const int* __restrict__ flag){
  int isbf = flag[0];
  int blk = blockIdx.x;
  const void* pWk = wp.p[7];  const void* pWv = wp.p[8];
  const void* pW1 = wp.p[21]; const void* pW2 = wp.p[23];
  for (int e = threadIdx.x; e < 8192; e += 256){
    int j = e & 7, lane = (e >> 3) & 63, frag = e >> 9;
    int qd = lane >> 4, l15 = lane & 15;
    if (blk == 0){           // [Wk|Wv]: K=64, N=128, frag = nt*2 + ks
      int nt = frag >> 1, ks = frag & 1;
      int k = ks*32 + qd*8 + j, n = nt*16 + l15;
      float v = (n < 64) ? ldin(pWk, k*64 + n, isbf) : ldin(pWv, k*64 + (n-64), isbf);
      fkv[e] = f2bf(v);
    } else if (blk == 1){    // pe_W1: K=64, N=128, frag = nt*2 + ks
      int nt = frag >> 1, ks = frag & 1;
      int k = ks*32 + qd*8 + j, n = nt*16 + l15;
      f1[e] = f2bf(ldin(pW1, k*128 + n, isbf));
    } else {                 // pe_W2: K=128, N=64, frag = nt*4 + s
      int nt = frag >> 2, s = frag & 3;
      int k = s*32 + qd*8 + j, n = nt*16 + l15;
      f2[e] = f2bf(ldin(pW2, k*64 + n, isbf));
    }
  }
}

// ---------------- kernel: input LN + [k|v] = LN(x) @ [Wk|Wv]  (MFMA, 256 rows/block) ----
__global__ __launch_bounds__(256) void k0a_kernel(const void* __restrict__ inpv,
                                                  const float* __restrict__ w,
                                                  const u16* __restrict__ fkv,
                                                  u16* __restrict__ kbuf,
                                                  u16* __restrict__ vbuf,
                                                  const int* __restrict__ flag){
  __shared__ __align__(16) u16 T[256*72];      // post-LN feats, bf16, stride 72
  int isbf = flag[0];
  int t = threadIdx.x;
  size_t row0 = (size_t)blockIdx.x * 256;

  { // LN, thread per row
    size_t row = row0 + t;
    float x[64];
    if (isbf){
      const u32* up = (const u32*)((const u16*)inpv + row*66);
#pragma unroll
      for (int c = 0; c < 32; c++){
        u32 v = up[c];
        x[2*c] = bf2f((u16)(v & 0xffffu)); x[2*c+1] = bf2f((u16)(v >> 16));
      }
    } else {
      const float2* fp = (const float2*)((const float*)inpv + row*66);
#pragma unroll
      for (int c = 0; c < 32; c++){ float2 v = fp[c]; x[2*c] = v.x; x[2*c+1] = v.y; }
    }
    float mu = 0.f;
#pragma unroll
    for (int i = 0; i < 64; i++) mu += x[i];
    mu *= (1.f/64.f);
    float va = 0.f;
#pragma unroll
    for (int i = 0; i < 64; i++){ x[i] -= mu; va += x[i]*x[i]; }
    va *= (1.f/64.f);
    float rs = rsqrtf(va + LN_EPS);
#pragma unroll
    for (int i = 0; i < 64; i++) x[i] = x[i]*rs*w[O_LNING+i] + w[O_LNINB+i];
    u32* T32 = (u32*)T;
#pragma unroll
    for (int c = 0; c < 32; c++) T32[t*36 + c] = pack2(x[2*c], x[2*c+1]);
  }
  __syncthreads();

  int lane = t & 63, wid = t >> 6, qd = lane >> 4, l15 = lane & 15;
  bf16x8 af[4][2];
#pragma unroll
  for (int mt = 0; mt < 4; mt++)
#pragma unroll
    for (int ks = 0; ks < 2; ks++)
      af[mt][ks] = *(const bf16x8*)&T[(wid*64 + mt*16 + l15)*72 + ks*32 + qd*8];

#pragma unroll
  for (int nt = 0; nt < 8; nt++){
    bf16x8 b0 = *(const bf16x8*)(fkv + ((size_t)(nt*2+0)*64 + lane)*8);
    bf16x8 b1 = *(const bf16x8*)(fkv + ((size_t)(nt*2+1)*64 + lane)*8);
    u16* ob = (nt < 4) ? kbuf : vbuf;
    int col = (nt*16 + l15) & 63;
#pragma unroll
    for (int mt = 0; mt < 4; mt++){
      f32x4 acc = {0.f,0.f,0.f,0.f};
      acc = MFMA(af[mt][0], b0, acc);
      acc = MFMA(af[mt][1], b1, acc);
      size_t rb = row0 + wid*64 + mt*16 + qd*4;
#pragma unroll
      for (int r = 0; r < 4; r++) ob[(rb+r)*64 + col] = f2bf(acc[r]);
    }
  }
}

// ---------------- kernel: positional-MLP (MFMA, 128 rows/block, in place) ------------
// out = relu(LN(x + grid_proj) @ W1 + b1) @ W2 + b2 ; per-wave H-slice through LDS.
__global__ __launch_bounds__(256) void k0b_kernel(const void* __restrict__ inpv,
                                                  const float* __restrict__ w,
                                                  const u16* __restrict__ f1,
                                                  const u16* __restrict__ f2,
                                                  u16* __restrict__ kbuf,
                                                  u16* __restrict__ vbuf,
                                                  const int* __restrict__ flag){
  __shared__ __align__(16) u16 T[128*72];       // LN output, bf16
  __shared__ __align__(16) u16 Hb[4*32*40];     // per-wave relu'd hidden slice
  int isbf = flag[0];
  int t = threadIdx.x;
  int isv = (blockIdx.x >= 4096);
  u16* base = isv ? vbuf : kbuf;
  size_t row0 = ((size_t)(blockIdx.x & 4095)) * 128;

  if (t < 128){ // LN phase: thread per row
    size_t row = row0 + t;
    float g0, g1;
    if (isbf){
      u32 gv = *(const u32*)((const u16*)inpv + row*66 + 64);
      g0 = bf2f((u16)(gv & 0xffffu)); g1 = bf2f((u16)(gv >> 16));
    } else {
      float2 gv = *(const float2*)((const float*)inpv + row*66 + 64);
      g0 = gv.x; g1 = gv.y;
    }
    float tv[64];
    const uint4* rp = (const uint4*)(base + row*64);
#pragma unroll
    for (int c = 0; c < 8; c++){ uint4 q4 = rp[c]; unpack8(q4, &tv[c*8]); }
#pragma unroll
    for (int i = 0; i < 64; i++)
      tv[i] += g0*w[O_PAW+i] + g1*w[O_PAW+64+i] + w[O_PAB+i];
    float mu = 0.f;
#pragma unroll
    for (int i = 0; i < 64; i++) mu += tv[i];
    mu *= (1.f/64.f);
    float va = 0.f;
#pragma unroll
    for (int i = 0; i < 64; i++){ tv[i] -= mu; va += tv[i]*tv[i]; }
    va *= (1.f/64.f);
    float rs = rsqrtf(va + LN_EPS);
#pragma unroll
    for (int i = 0; i < 64; i++) tv[i] = tv[i]*rs*w[O_PEG+i] + w[O_PEB+i];
    u32* T32 = (u32*)T;
#pragma unroll
    for (int c = 0; c < 32; c++) T32[t*36 + c] = pack2(tv[2*c], tv[2*c+1]);
  }
  __syncthreads();

  int lane = t & 63, wid = t >> 6, qd = lane >> 4, l15 = lane & 15;
  u16* Hw = Hb + wid*32*40;                       // this wave's 32 rows x 40 slice

  bf16x8 af[2][2];
#pragma unroll
  for (int mt = 0; mt < 2; mt++)
#pragma unroll
    for (int ks = 0; ks < 2; ks++)
      af[mt][ks] = *(const bf16x8*)&T[(wid*32 + mt*16 + l15)*72 + ks*32 + qd*8];

  f32x4 out[2][4];
#pragma unroll
  for (int mt = 0; mt < 2; mt++)
#pragma unroll
    for (int nt = 0; nt < 4; nt++) out[mt][nt] = (f32x4){0.f,0.f,0.f,0.f};

#pragma unroll
  for (int s = 0; s < 4; s++){                    // hidden slice of 32
#pragma unroll
    for (int e = 0; e < 2; e++){                  // two 16-wide GEMM1 n-tiles
      int nn = s*2 + e;
      bf16x8 b0 = *(const bf16x8*)(f1 + ((size_t)(nn*2+0)*64 + lane)*8);
      bf16x8 b1 = *(const bf16x8*)(f1 + ((size_t)(nn*2+1)*64 + lane)*8);
#pragma unroll
      for (int mt = 0; mt < 2; mt++){
        f32x4 h = {0.f,0.f,0.f,0.f};
        h = MFMA(af[mt][0], b0, h);
        h = MFMA(af[mt][1], b1, h);
        float bias1 = w[O_PEB1 + nn*16 + l15];
#pragma unroll
        for (int r = 0; r < 4; r++)
          Hw[(mt*16 + qd*4 + r)*40 + e*16 + l15] = f2bf(fmaxf(h[r] + bias1, 0.f));
      }
    }
    // same-wave RAW through LDS: lgkmcnt ordering, no barrier needed
    bf16x8 a2[2];
#pragma unroll
    for (int mt = 0; mt < 2; mt++)
      a2[mt] = *(const bf16x8*)&Hw[(mt*16 + l15)*40 + qd*8];
#pragma unroll
    for (int nt = 0; nt < 4; nt++){
      bf16x8 bw = *(const bf16x8*)(f2 + ((size_t)(nt*4 + s)*64 + lane)*8);
#pragma unroll
      for (int mt = 0; mt < 2; mt++)
        out[mt][nt] = MFMA(a2[mt], bw, out[mt][nt]);
    }
  }

#pragma unroll
  for (int nt = 0; nt < 4; nt++){
    float b2v = w[O_PEB2 + nt*16 + l15];
#pragma unroll
    for (int mt = 0; mt < 2; mt++){
      size_t rb = row0 + wid*32 + mt*16 + qd*4;
#pragma unroll
      for (int r = 0; r < 4; r++)
        base[(rb+r)*64 + nt*16 + l15] = f2bf(out[mt][nt][r] + b2v);
    }
  }
}

// ---------------- kernel: q = LN(state)@Wq ; zero accumulators (wave per slot-row) ----
__global__ __launch_bounds__(64) void b1_kernel(const float* __restrict__ w,
                                                const float* __restrict__ state,
                                                float* __restrict__ qbuf,
                                                float* __restrict__ upd,
                                                float* __restrict__ sums){
  int rrow = blockIdx.x;          // [0,256) = b*8+s
  int lane = threadIdx.x;
  float xv = state[rrow*64 + lane];
  float sum = xv;
#pragma unroll
  for (int off = 32; off; off >>= 1) sum += __shfl_xor(sum, off, 64);
  float mu = sum * (1.f/64.f);
  float xc = xv - mu;
  float ss = xc*xc;
#pragma unroll
  for (int off = 32; off; off >>= 1) ss += __shfl_xor(ss, off, 64);
  float rs = rsqrtf(ss*(1.f/64.f) + LN_EPS);
  float xln = xc*rs*w[O_LNSG+lane] + w[O_LNSB+lane];
  float acc = 0.f;
#pragma unroll
  for (int i = 0; i < 64; i++){
    float xi = __shfl(xln, i, 64);
    acc += xi * w[O_WQ + i*64 + lane];
  }
  qbuf[rrow*64 + lane] = acc;
  upd[rrow*64 + lane]  = 0.f;
  if (lane == 0) sums[rrow] = 0.f;
}

// ---------------- kernel: attention pass (512 n per block) ----------------
__global__ __launch_bounds__(512) void b2_kernel(const u16* __restrict__ kbuf,
                                                 const u16* __restrict__ vbuf,
                                                 const float* __restrict__ qbuf,
                                                 float* __restrict__ upd,
                                                 float* __restrict__ sums){
  __shared__ float qs[512];
  __shared__ float pmat[8*512];
  int t  = threadIdx.x;
  int b  = blockIdx.x >> 5;
  int n0 = (blockIdx.x & 31) << 9;

  qs[t] = qbuf[b*512 + t];
  __syncthreads();

  size_t n = (size_t)b*NN + n0 + t;
  float kreg[64];
  const uint4* kp = (const uint4*)(kbuf + n*64);
#pragma unroll
  for (int c = 0; c < 8; c++){ uint4 v = kp[c]; unpack8(v, &kreg[c*8]); }

  float l[8];
#pragma unroll
  for (int s = 0; s < 8; s++){
    float a = 0.f;
#pragma unroll
    for (int i = 0; i < 64; i++) a += kreg[i]*qs[s*64+i];
    l[s] = a * 0.125f;
  }
  float m = l[0];
#pragma unroll
  for (int s = 1; s < 8; s++) m = fmaxf(m, l[s]);
  float esum = 0.f;
#pragma unroll
  for (int s = 0; s < 8; s++){ l[s] = __expf(l[s]-m); esum += l[s]; }
  float inv = 1.f/esum;
#pragma unroll
  for (int s = 0; s < 8; s++) pmat[s*512 + t] = l[s]*inv + 1e-8f;
  __syncthreads();

  int s = t >> 6, d = t & 63;
  float part = 0.f;
#pragma unroll
  for (int c = 0; c < 8; c++) part += pmat[s*512 + c*64 + d];
#pragma unroll
  for (int off = 32; off; off >>= 1) part += __shfl_xor(part, off, 64);
  if (d == 0) atomicAdd(&sums[b*8 + s], part);

  const u16* vp = vbuf + ((size_t)b*NN + n0)*64 + d;
  float acc = 0.f;
#pragma unroll 8
  for (int j = 0; j < 512; j++)
    acc += pmat[s*512 + j] * bf2f(vp[(size_t)j*64]);
  atomicAdd(&upd[b*512 + s*64 + d], acc);
}

// ---------------- kernel: GRU + residual MLP state update (block per batch) ----------
__global__ __launch_bounds__(256) void b3_kernel(const float* __restrict__ w,
                                                 float* __restrict__ state,
                                                 const float* __restrict__ upd,
                                                 const float* __restrict__ sums){
  __shared__ float uL[512], pL[512], gxL[1536], ghL[1536], hL[512], hidL[1024];
  __shared__ float muL[8], rsL[8];
  int t = threadIdx.x, b = blockIdx.x;

#pragma unroll
  for (int e = 0; e < 2; e++){
    int idx = t + 256*e; int s = idx >> 6;
    uL[idx] = upd[b*512 + idx] / sums[b*8 + s];
    pL[idx] = state[b*512 + idx];
  }
  __syncthreads();

  for (int e = 0; e < 6; e++){
    int idx = t + 256*e; int s = idx/192, j = idx - s*192;
    float ax = w[O_BIH + j], ah = w[O_BHH + j];
    for (int d = 0; d < 64; d++){
      ax += uL[s*64+d] * w[O_WIH + d*192 + j];
      ah += pL[s*64+d] * w[O_WHH + d*192 + j];
    }
    gxL[idx] = ax; ghL[idx] = ah;
  }
  __syncthreads();

#pragma unroll
  for (int e = 0; e < 2; e++){
    int idx = t + 256*e; int s = idx >> 6, d = idx & 63;
    float xr = gxL[s*192+d],     hr = ghL[s*192+d];
    float xz = gxL[s*192+64+d],  hz = ghL[s*192+64+d];
    float xn = gxL[s*192+128+d], hn = ghL[s*192+128+d];
    float r = 1.f/(1.f + expf(-(xr+hr)));
    float z = 1.f/(1.f + expf(-(xz+hz)));
    float nv = tanhf(xn + r*hn);
    hL[idx] = (1.f - z)*nv + z*pL[idx];
  }
  __syncthreads();

  if (t < 8){
    float mu = 0.f;
    for (int d = 0; d < 64; d++) mu += hL[t*64+d];
    mu *= (1.f/64.f);
    float va = 0.f;
    for (int d = 0; d < 64; d++){ float c = hL[t*64+d]-mu; va += c*c; }
    muL[t] = mu; rsL[t] = rsqrtf(va*(1.f/64.f) + LN_EPS);
  }
  __syncthreads();

  for (int e = 0; e < 4; e++){
    int idx = t + 256*e; int s = idx >> 7, j = idx & 127;
    float a = w[O_MLPB1 + j];
    for (int d = 0; d < 64; d++){
      float xln = (hL[s*64+d]-muL[s])*rsL[s]*w[O_LNMG+d] + w[O_LNMB+d];
      a += xln * w[O_MLPW1 + d*128 + j];
    }
    hidL[idx] = fmaxf(a, 0.f);
  }
  __syncthreads();

#pragma unroll
  for (int e = 0; e < 2; e++){
    int idx = t + 256*e; int s = idx >> 6, d = idx & 63;
    float o = w[O_MLPB2 + d];
    for (int j = 0; j < 128; j++) o += hidL[s*128+j] * w[O_MLPW2 + j*64 + d];
    state[b*512 + idx] = hL[idx] + o;
  }
}

// ---------------- kernel: state (fp32) -> out (bf16 or fp32 per flag) ----------------
__global__ __launch_bounds__(256) void kout_kernel(const float* __restrict__ state,
                                                   void* __restrict__ out,
                                                   const int* __restrict__ flag){
  int i = blockIdx.x*256 + threadIdx.x;
  if (flag[0]) ((u16*)out)[i] = f2bf(state[i]);
  else         ((float*)out)[i] = state[i];
}

// ---------------- launch ----------------
extern "C" void kernel_launch(void* const* d_in, const int* in_sizes, int n_in,
                              void* d_out, int out_size, void* d_ws, size_t ws_size,
                              hipStream_t stream){
  const void* inp   = d_in[0];
  const void* slots = d_in[1];
  WP wp;
  for (int i = 0; i < 25; i++) wp.p[i] = d_in[2+i];

  u16*   kbuf  = (u16*)d_ws;                         // BN*64 bf16 (k -> k_pos in place)
  u16*   vbuf  = kbuf + (size_t)BN*64;               // BN*64 bf16 (v -> v_pos in place)
  float* w     = (float*)(vbuf + (size_t)BN*64);     // fp32 weight arena
  float* state = w + W_TOTAL;                        // 32*8*64
  float* qbuf  = state + 16384;
  float* upd   = qbuf + 16384;
  float* sums  = upd + 16384;                        // 256
  u16*   fkv   = (u16*)(sums + 256);                 // 16 frags * 512 bf16
  u16*   f1    = fkv + 8192;
  u16*   f2    = f1 + 8192;
  int*   flag  = (int*)(f2 + 8192);

  kdetect_kernel<<<1, 64, 0, stream>>>((const u16*)inp, flag);
  kw_kernel<<<26, 256, 0, stream>>>(wp, w, state, slots, flag);
  kpack_kernel<<<3, 256, 0, stream>>>(wp, fkv, f1, f2, flag);
  k0a_kernel<<<2048, 256, 0, stream>>>(inp, w, fkv, kbuf, vbuf, flag);
  k0b_kernel<<<8192, 256, 0, stream>>>(inp, w, f1, f2, kbuf, vbuf, flag);
  for (int it = 0; it < 3; it++){
    b1_kernel<<<256, 64, 0, stream>>>(w, state, qbuf, upd, sums);
    b2_kernel<<<1024, 512, 0, stream>>>(kbuf, vbuf, qbuf, upd, sums);
    b3_kernel<<<32, 256, 0, stream>>>(w, state, upd, sums);
  }
  kout_kernel<<<64, 256, 0, stream>>>(state, d_out, flag);
}

// Round 4
// 706.645 us; speedup vs baseline: 2.5422x; 1.0565x over previous
//
#include <hip/hip_runtime.h>

typedef unsigned short u16;
typedef unsigned int   u32;

#define NN 16384
#define BN 524288      /* B*N = 32*16384 */
#define LN_EPS 1e-5f

typedef __attribute__((ext_vector_type(8))) short bf16x8;
typedef __attribute__((ext_vector_type(4))) float f32x4;
#define MFMA(a,b,c) __builtin_amdgcn_mfma_f32_16x16x32_bf16(a,b,c,0,0,0)

// ---------------- helpers ----------------
__device__ __forceinline__ float bf2f(u16 h){
  union { u32 u; float f; } c; c.u = ((u32)h) << 16; return c.f;
}
__device__ __forceinline__ u16 f2bf(float f){
  union { float f; u32 u; } c; c.f = f;
  u32 r = (c.u + 0x7fffu + ((c.u >> 16) & 1u)) >> 16;   // RNE
  return (u16)r;
}
__device__ __forceinline__ u32 pack2(float a, float b){
  return (u32)f2bf(a) | ((u32)f2bf(b) << 16);
}
__device__ __forceinline__ void unpack8(uint4 v, float* o){
  o[0]=bf2f((u16)(v.x&0xffffu)); o[1]=bf2f((u16)(v.x>>16));
  o[2]=bf2f((u16)(v.y&0xffffu)); o[3]=bf2f((u16)(v.y>>16));
  o[4]=bf2f((u16)(v.z&0xffffu)); o[5]=bf2f((u16)(v.z>>16));
  o[6]=bf2f((u16)(v.w&0xffffu)); o[7]=bf2f((u16)(v.w>>16));
}
__device__ __forceinline__ float ldin(const void* p, int i, int isbf){
  return isbf ? bf2f(((const u16*)p)[i]) : ((const float*)p)[i];
}

// ---------------- fp32 weight arena offsets (floats) ----------------
enum {
  O_LNING=0, O_LNINB=64, O_LNSG=128, O_LNSB=192, O_LNMG=256, O_LNMB=320,
  O_WQ=384, O_WK=4480, O_WV=8576,
  O_WIH=12672, O_WHH=24960, O_BIH=37248, O_BHH=37440,
  O_MLPW1=37632, O_MLPB1=45824, O_MLPW2=45952, O_MLPB2=54144,
  O_PAW=54208, O_PAB=54336,
  O_PEG=54400, O_PEB=54464, O_PEW1=54528, O_PEB1=62720, O_PEW2=62848, O_PEB2=71040,
  W_TOTAL=71104
};
__device__ const int g_woff[25] = {O_LNING,O_LNINB,O_LNSG,O_LNSB,O_LNMG,O_LNMB,
  O_WQ,O_WK,O_WV,O_WIH,O_WHH,O_BIH,O_BHH,O_MLPW1,O_MLPB1,O_MLPW2,O_MLPB2,
  O_PAW,O_PAB,O_PEG,O_PEB,O_PEW1,O_PEB1,O_PEW2,O_PEB2};
__device__ const int g_wsz[25]  = {64,64,64,64,64,64,4096,4096,4096,12288,12288,
  192,192,8192,128,8192,64,128,64,64,64,8192,128,8192,64};

struct WP { const void* p[25]; };

// ---------------- kernel: detect input dtype ----------------
__global__ void kdetect_kernel(const u16* __restrict__ inp, int* __restrict__ flag){
  if (threadIdx.x == 0 && blockIdx.x == 0){
    int votes = 0;
    for (int i = 0; i < 64; i++){
      u16 h = inp[2*i];
      int e = (h >> 7) & 0xff;
      int m = h & 0x7f;
      if ((e == 0 && m == 0) || (e >= 100 && e <= 144)) votes++;
    }
    flag[0] = (votes >= 48) ? 1 : 0;   // 1 = bf16, 0 = fp32
  }
}

// ---------------- kernel: weight convert (->fp32 arena) + state init ----------------
__global__ __launch_bounds__(256) void kw_kernel(WP wp, float* __restrict__ w,
                                                 float* __restrict__ state,
                                                 const void* __restrict__ slots,
                                                 const int* __restrict__ flag){
  int isbf = flag[0];
  int blk = blockIdx.x;
  if (blk < 25){
    const void* src = wp.p[blk];
    int off = g_woff[blk], sz = g_wsz[blk];
    for (int i = threadIdx.x; i < sz; i += 256)
      w[off + i] = ldin(src, i, isbf);
  } else {
    for (int i = threadIdx.x; i < 512; i += 256){
      float sv = ldin(slots, i, isbf);
      for (int b = 0; b < 32; b++) state[b*512 + i] = sv;
    }
  }
}

// ---------------- kernel: pack B-fragment buffers (bf16, MFMA B-layout) ----------------
// B-frag for mfma_f32_16x16x32_bf16: lane holds B[k][n] with n = ntile*16 + (lane&15),
// k = kstep*32 + (lane>>4)*8 + j (j=0..7). Stored frag-major: fb[frag*512 + lane*8 + j].
__global__ __launch_bounds__(256) void kpack_kernel(WP wp, u16* __restrict__ fkv,
                                                    u16* __restrict__ f1,
                                                    u16* __restrict__ f2,
                                                    const int* __restrict__ flag){
  int isbf = flag[0];
  int blk = blockIdx.x;
  const void* pWk = wp.p[7];  const void* pWv = wp.p[8];
  const void* pW1 = wp.p[21]; const void* pW2 = wp.p[23];
  for (int e = threadIdx.x; e < 8192; e += 256){
    int j = e & 7, lane = (e >> 3) & 63, frag = e >> 9;
    int qd = lane >> 4, l15 = lane & 15;
    if (blk == 0){           // [Wk|Wv]: K=64, N=128, frag = nt*2 + ks
      int nt = frag >> 1, ks = frag & 1;
      int k = ks*32 + qd*8 + j, n = nt*16 + l15;
      float v = (n < 64) ? ldin(pWk, k*64 + n, isbf) : ldin(pWv, k*64 + (n-64), isbf);
      fkv[e] = f2bf(v);
    } else if (blk == 1){    // pe_W1: K=64, N=128, frag = nt*2 + ks
      int nt = frag >> 1, ks = frag & 1;
      int k = ks*32 + qd*8 + j, n = nt*16 + l15;
      f1[e] = f2bf(ldin(pW1, k*128 + n, isbf));
    } else {                 // pe_W2: K=128, N=64, frag = nt*4 + s
      int nt = frag >> 2, s = frag & 3;
      int k = s*32 + qd*8 + j, n = nt*16 + l15;
      f2[e] = f2bf(ldin(pW2, k*64 + n, isbf));
    }
  }
}

// ============== FUSED kernel: LN + [k|v] GEMM + pos-enc MLP (128 rows/block) ==========
// Phases: P1 LN(feats)->T1 | P2 MFMA [k|v]->KV(LDS) | P3 grid_proj+LN (regs) -> T2
// (T2 reuses KV region after a barrier) | P4 MFMA MLP -> k_pos/v_pos global.
#define KVS 136                 /* KV row stride in u16 (128 cols + pad, mult of 8) */
__global__ __launch_bounds__(256) void k0_kernel(const void* __restrict__ inpv,
                                                 const float* __restrict__ w,
                                                 const u16* __restrict__ fkv,
                                                 const u16* __restrict__ f1,
                                                 const u16* __restrict__ f2,
                                                 u16* __restrict__ kbuf,
                                                 u16* __restrict__ vbuf,
                                                 const int* __restrict__ flag){
  __shared__ __align__(16) u16 shA[128*72];    // T1, later Hw          (18432 B)
  __shared__ __align__(16) u16 shB[256*72];    // KV (128 x KVS), later T2 (36864 B)
  __shared__ float gbuf[256];                  // grid coords           (1024 B)
  int isbf = flag[0];
  int t = threadIdx.x;
  size_t row0 = (size_t)blockIdx.x * 128;
  int lane = t & 63, wid = t >> 6, qd = lane >> 4, l15 = lane & 15;

  // ---- P1: LN(feats) thread-per-row (128 rows) ----
  if (t < 128){
    size_t row = row0 + t;
    float x[64], g0, g1;
    if (isbf){
      const u32* up = (const u32*)((const u16*)inpv + row*66);
#pragma unroll
      for (int c = 0; c < 32; c++){
        u32 v = up[c];
        x[2*c] = bf2f((u16)(v & 0xffffu)); x[2*c+1] = bf2f((u16)(v >> 16));
      }
      u32 gv = up[32];
      g0 = bf2f((u16)(gv & 0xffffu)); g1 = bf2f((u16)(gv >> 16));
    } else {
      const float2* fp = (const float2*)((const float*)inpv + row*66);
#pragma unroll
      for (int c = 0; c < 32; c++){ float2 v = fp[c]; x[2*c] = v.x; x[2*c+1] = v.y; }
      float2 gv = fp[32]; g0 = gv.x; g1 = gv.y;
    }
    gbuf[2*t] = g0; gbuf[2*t+1] = g1;
    float mu = 0.f;
#pragma unroll
    for (int i = 0; i < 64; i++) mu += x[i];
    mu *= (1.f/64.f);
    float va = 0.f;
#pragma unroll
    for (int i = 0; i < 64; i++){ x[i] -= mu; va += x[i]*x[i]; }
    va *= (1.f/64.f);
    float rs = rsqrtf(va + LN_EPS);
#pragma unroll
    for (int i = 0; i < 64; i++) x[i] = x[i]*rs*w[O_LNING+i] + w[O_LNINB+i];
    u32* T32 = (u32*)shA;
#pragma unroll
    for (int c = 0; c < 32; c++) T32[t*36 + c] = pack2(x[2*c], x[2*c+1]);
  }
  __syncthreads();

  // ---- P2: [k|v] = T1 @ fkv -> KV in shB (stride KVS) ----
  {
    bf16x8 af[2][2];
#pragma unroll
    for (int mt = 0; mt < 2; mt++)
#pragma unroll
      for (int ks = 0; ks < 2; ks++)
        af[mt][ks] = *(const bf16x8*)&shA[(wid*32 + mt*16 + l15)*72 + ks*32 + qd*8];
#pragma unroll
    for (int nt = 0; nt < 8; nt++){
      bf16x8 b0 = *(const bf16x8*)(fkv + ((size_t)(nt*2+0)*64 + lane)*8);
      bf16x8 b1 = *(const bf16x8*)(fkv + ((size_t)(nt*2+1)*64 + lane)*8);
#pragma unroll
      for (int mt = 0; mt < 2; mt++){
        f32x4 acc = {0.f,0.f,0.f,0.f};
        acc = MFMA(af[mt][0], b0, acc);
        acc = MFMA(af[mt][1], b1, acc);
        int rb = wid*32 + mt*16 + qd*4;
#pragma unroll
        for (int r = 0; r < 4; r++) shB[(rb+r)*KVS + nt*16 + l15] = f2bf(acc[r]);
      }
    }
  }
  __syncthreads();

  // ---- P3a: pos-enc input LN in registers (256 virtual rows: 0-127 k, 128-255 v) ----
  float tv[64];
  {
    int phys = t & 127, isv3 = t >> 7;
    float g0 = gbuf[2*phys], g1 = gbuf[2*phys+1];
    const uint4* rp = (const uint4*)&shB[phys*KVS + isv3*64];
#pragma unroll
    for (int c = 0; c < 8; c++){ uint4 q4 = rp[c]; unpack8(q4, &tv[c*8]); }
#pragma unroll
    for (int i = 0; i < 64; i++)
      tv[i] += g0*w[O_PAW+i] + g1*w[O_PAW+64+i] + w[O_PAB+i];
    float mu = 0.f;
#pragma unroll
    for (int i = 0; i < 64; i++) mu += tv[i];
    mu *= (1.f/64.f);
    float va = 0.f;
#pragma unroll
    for (int i = 0; i < 64; i++){ tv[i] -= mu; va += tv[i]*tv[i]; }
    va *= (1.f/64.f);
    float rs = rsqrtf(va + LN_EPS);
#pragma unroll
    for (int i = 0; i < 64; i++) tv[i] = tv[i]*rs*w[O_PEG+i] + w[O_PEB+i];
  }
  __syncthreads();          // all KV reads done; shB may be overwritten

  // ---- P3b: write T2 into shB (256 rows x stride 72) ----
  {
    u32* T32 = (u32*)shB;
#pragma unroll
    for (int c = 0; c < 32; c++) T32[t*36 + c] = pack2(tv[2*c], tv[2*c+1]);
  }
  __syncthreads();

  // ---- P4: MLP = relu(T2@W1+b1)@W2+b2 ; wave covers 64 virtual rows ----
  {
    u16* Hw = shA + wid*(64*32);               // 64 rows x 32 u16 slice per wave
    bf16x8 af[4][2];
#pragma unroll
    for (int mt = 0; mt < 4; mt++)
#pragma unroll
      for (int ks = 0; ks < 2; ks++)
        af[mt][ks] = *(const bf16x8*)&shB[(wid*64 + mt*16 + l15)*72 + ks*32 + qd*8];

    f32x4 out[4][4];
#pragma unroll
    for (int mt = 0; mt < 4; mt++)
#pragma unroll
      for (int nt = 0; nt < 4; nt++) out[mt][nt] = (f32x4){0.f,0.f,0.f,0.f};

#pragma unroll
    for (int s = 0; s < 4; s++){               // hidden slice of 32
#pragma unroll
      for (int e = 0; e < 2; e++){
        int nn = s*2 + e;
        bf16x8 b0 = *(const bf16x8*)(f1 + ((size_t)(nn*2+0)*64 + lane)*8);
        bf16x8 b1 = *(const bf16x8*)(f1 + ((size_t)(nn*2+1)*64 + lane)*8);
        float bias1 = w[O_PEB1 + nn*16 + l15];
#pragma unroll
        for (int mt = 0; mt < 4; mt++){
          f32x4 h = {0.f,0.f,0.f,0.f};
          h = MFMA(af[mt][0], b0, h);
          h = MFMA(af[mt][1], b1, h);
#pragma unroll
          for (int r = 0; r < 4; r++)
            Hw[(mt*16 + qd*4 + r)*32 + e*16 + l15] = f2bf(fmaxf(h[r] + bias1, 0.f));
        }
      }
      // same-wave RAW through LDS (lgkmcnt-ordered, no barrier)
      bf16x8 a2[4];
#pragma unroll
      for (int mt = 0; mt < 4; mt++)
        a2[mt] = *(const bf16x8*)&Hw[(mt*16 + l15)*32 + qd*8];
#pragma unroll
      for (int nt = 0; nt < 4; nt++){
        bf16x8 bw = *(const bf16x8*)(f2 + ((size_t)(nt*4 + s)*64 + lane)*8);
#pragma unroll
        for (int mt = 0; mt < 4; mt++)
          out[mt][nt] = MFMA(a2[mt], bw, out[mt][nt]);
      }
    }

    u16* ob = (wid >> 1) ? vbuf : kbuf;
    size_t rbase = row0 + (size_t)(wid & 1)*64;
#pragma unroll
    for (int nt = 0; nt < 4; nt++){
      float b2v = w[O_PEB2 + nt*16 + l15];
#pragma unroll
      for (int mt = 0; mt < 4; mt++){
        size_t rb = rbase + mt*16 + qd*4;
#pragma unroll
        for (int r = 0; r < 4; r++)
          ob[(rb+r)*64 + nt*16 + l15] = f2bf(out[mt][nt][r] + b2v);
      }
    }
  }
}

// ---------------- kernel: q = LN(state)@Wq ; zero accumulators (wave per slot-row) ----
__global__ __launch_bounds__(64) void b1_kernel(const float* __restrict__ w,
                                                const float* __restrict__ state,
                                                float* __restrict__ qbuf,
                                                float* __restrict__ upd,
                                                float* __restrict__ sums){
  int rrow = blockIdx.x;          // [0,256) = b*8+s
  int lane = threadIdx.x;
  float xv = state[rrow*64 + lane];
  float sum = xv;
#pragma unroll
  for (int off = 32; off; off >>= 1) sum += __shfl_xor(sum, off, 64);
  float mu = sum * (1.f/64.f);
  float xc = xv - mu;
  float ss = xc*xc;
#pragma unroll
  for (int off = 32; off; off >>= 1) ss += __shfl_xor(ss, off, 64);
  float rs = rsqrtf(ss*(1.f/64.f) + LN_EPS);
  float xln = xc*rs*w[O_LNSG+lane] + w[O_LNSB+lane];
  float acc = 0.f;
#pragma unroll
  for (int i = 0; i < 64; i++){
    float xi = __shfl(xln, i, 64);
    acc += xi * w[O_WQ + i*64 + lane];
  }
  qbuf[rrow*64 + lane] = acc;
  upd[rrow*64 + lane]  = 0.f;
  if (lane == 0) sums[rrow] = 0.f;
}

// ---------------- kernel: attention pass (512 n per block) ----------------
__global__ __launch_bounds__(512) void b2_kernel(const u16* __restrict__ kbuf,
                                                 const u16* __restrict__ vbuf,
                                                 const float* __restrict__ qbuf,
                                                 float* __restrict__ upd,
                                                 float* __restrict__ sums){
  __shared__ float qs[512];
  __shared__ float pmat[8*512];
  int t  = threadIdx.x;
  int b  = blockIdx.x >> 5;
  int n0 = (blockIdx.x & 31) << 9;

  qs[t] = qbuf[b*512 + t];
  __syncthreads();

  // phase A: thread-per-n logits + softmax over S=8
  size_t n = (size_t)b*NN + n0 + t;
  float kreg[64];
  const uint4* kp = (const uint4*)(kbuf + n*64);
#pragma unroll
  for (int c = 0; c < 8; c++){ uint4 v = kp[c]; unpack8(v, &kreg[c*8]); }

  float l[8];
#pragma unroll
  for (int s = 0; s < 8; s++){
    float a = 0.f;
#pragma unroll
    for (int i = 0; i < 64; i++) a += kreg[i]*qs[s*64+i];
    l[s] = a * 0.125f;
  }
  float m = l[0];
#pragma unroll
  for (int s = 1; s < 8; s++) m = fmaxf(m, l[s]);
  float esum = 0.f;
#pragma unroll
  for (int s = 0; s < 8; s++){ l[s] = __expf(l[s]-m); esum += l[s]; }
  float inv = 1.f/esum;
#pragma unroll
  for (int s = 0; s < 8; s++) pmat[s*512 + t] = l[s]*inv + 1e-8f;
  __syncthreads();

  // phase B: wave s handles slot s; lane = (jg = lane>>3 row-in-step, dg = lane&7 d-group)
  int s = t >> 6, lane = t & 63;

  float part = 0.f;
#pragma unroll
  for (int c = 0; c < 8; c++) part += pmat[s*512 + c*64 + lane];
#pragma unroll
  for (int off = 32; off; off >>= 1) part += __shfl_xor(part, off, 64);
  if (lane == 0) atomicAdd(&sums[b*8 + s], part);

  int dg = lane & 7, jg = lane >> 3;
  const u16* vp = vbuf + ((size_t)b*NN + n0)*64;
  float acc[8] = {0.f,0.f,0.f,0.f,0.f,0.f,0.f,0.f};
#pragma unroll 4
  for (int step = 0; step < 64; step++){
    int j = step*8 + jg;
    float p = pmat[s*512 + j];                       // 8-addr LDS broadcast
    uint4 vv = *(const uint4*)(vp + (size_t)j*64 + dg*8);  // wave: 1KB contiguous
    float vf[8]; unpack8(vv, vf);
#pragma unroll
    for (int i = 0; i < 8; i++) acc[i] += p * vf[i];
  }
#pragma unroll
  for (int off = 8; off < 64; off <<= 1)
#pragma unroll
    for (int i = 0; i < 8; i++) acc[i] += __shfl_xor(acc[i], off, 64);
  if (jg == 0){
    float* up = &upd[b*512 + s*64 + dg*8];
#pragma unroll
    for (int i = 0; i < 8; i++) atomicAdd(&up[i], acc[i]);
  }
}

// ---------------- kernel: GRU + residual MLP state update (block per batch) ----------
__global__ __launch_bounds__(256) void b3_kernel(const float* __restrict__ w,
                                                 float* __restrict__ state,
                                                 const float* __restrict__ upd,
                                                 const float* __restrict__ sums){
  __shared__ float uL[512], pL[512], gxL[1536], ghL[1536], hL[512], hidL[1024];
  __shared__ float muL[8], rsL[8];
  int t = threadIdx.x, b = blockIdx.x;

#pragma unroll
  for (int e = 0; e < 2; e++){
    int idx = t + 256*e; int s = idx >> 6;
    uL[idx] = upd[b*512 + idx] / sums[b*8 + s];
    pL[idx] = state[b*512 + idx];
  }
  __syncthreads();

  for (int e = 0; e < 6; e++){
    int idx = t + 256*e; int s = idx/192, j = idx - s*192;
    float ax = w[O_BIH + j], ah = w[O_BHH + j];
    for (int d = 0; d < 64; d++){
      ax += uL[s*64+d] * w[O_WIH + d*192 + j];
      ah += pL[s*64+d] * w[O_WHH + d*192 + j];
    }
    gxL[idx] = ax; ghL[idx] = ah;
  }
  __syncthreads();

#pragma unroll
  for (int e = 0; e < 2; e++){
    int idx = t + 256*e; int s = idx >> 6, d = idx & 63;
    float xr = gxL[s*192+d],     hr = ghL[s*192+d];
    float xz = gxL[s*192+64+d],  hz = ghL[s*192+64+d];
    float xn = gxL[s*192+128+d], hn = ghL[s*192+128+d];
    float r = 1.f/(1.f + expf(-(xr+hr)));
    float z = 1.f/(1.f + expf(-(xz+hz)));
    float nv = tanhf(xn + r*hn);
    hL[idx] = (1.f - z)*nv + z*pL[idx];
  }
  __syncthreads();

  if (t < 8){
    float mu = 0.f;
    for (int d = 0; d < 64; d++) mu += hL[t*64+d];
    mu *= (1.f/64.f);
    float va = 0.f;
    for (int d = 0; d < 64; d++){ float c = hL[t*64+d]-mu; va += c*c; }
    muL[t] = mu; rsL[t] = rsqrtf(va*(1.f/64.f) + LN_EPS);
  }
  __syncthreads();

  for (int e = 0; e < 4; e++){
    int idx = t + 256*e; int s = idx >> 7, j = idx & 127;
    float a = w[O_MLPB1 + j];
    for (int d = 0; d < 64; d++){
      float xln = (hL[s*64+d]-muL[s])*rsL[s]*w[O_LNMG+d] + w[O_LNMB+d];
      a += xln * w[O_MLPW1 + d*128 + j];
    }
    hidL[idx] = fmaxf(a, 0.f);
  }
  __syncthreads();

#pragma unroll
  for (int e = 0; e < 2; e++){
    int idx = t + 256*e; int s = idx >> 6, d = idx & 63;
    float o = w[O_MLPB2 + d];
    for (int j = 0; j < 128; j++) o += hidL[s*128+j] * w[O_MLPW2 + j*64 + d];
    state[b*512 + idx] = hL[idx] + o;
  }
}

// ---------------- kernel: state (fp32) -> out (bf16 or fp32 per flag) ----------------
__global__ __launch_bounds__(256) void kout_kernel(const float* __restrict__ state,
                                                   void* __restrict__ out,
                                                   const int* __restrict__ flag){
  int i = blockIdx.x*256 + threadIdx.x;
  if (flag[0]) ((u16*)out)[i] = f2bf(state[i]);
  else         ((float*)out)[i] = state[i];
}

// ---------------- launch ----------------
extern "C" void kernel_launch(void* const* d_in, const int* in_sizes, int n_in,
                              void* d_out, int out_size, void* d_ws, size_t ws_size,
                              hipStream_t stream){
  const void* inp   = d_in[0];
  const void* slots = d_in[1];
  WP wp;
  for (int i = 0; i < 25; i++) wp.p[i] = d_in[2+i];

  u16*   kbuf  = (u16*)d_ws;                         // BN*64 bf16 (k_pos)
  u16*   vbuf  = kbuf + (size_t)BN*64;               // BN*64 bf16 (v_pos)
  float* w     = (float*)(vbuf + (size_t)BN*64);     // fp32 weight arena
  float* state = w + W_TOTAL;                        // 32*8*64
  float* qbuf  = state + 16384;
  float* upd   = qbuf + 16384;
  float* sums  = upd + 16384;                        // 256
  u16*   fkv   = (u16*)(sums + 256);                 // 16 frags * 512 bf16
  u16*   f1    = fkv + 8192;
  u16*   f2    = f1 + 8192;
  int*   flag  = (int*)(f2 + 8192);

  kdetect_kernel<<<1, 64, 0, stream>>>((const u16*)inp, flag);
  kw_kernel<<<26, 256, 0, stream>>>(wp, w, state, slots, flag);
  kpack_kernel<<<3, 256, 0, stream>>>(wp, fkv, f1, f2, flag);
  k0_kernel<<<4096, 256, 0, stream>>>(inp, w, fkv, f1, f2, kbuf, vbuf, flag);
  for (int it = 0; it < 3; it++){
    b1_kernel<<<256, 64, 0, stream>>>(w, state, qbuf, upd, sums);
    b2_kernel<<<1024, 512, 0, stream>>>(kbuf, vbuf, qbuf, upd, sums);
    b3_kernel<<<32, 256, 0, stream>>>(w, state, upd, sums);
  }
  kout_kernel<<<64, 256, 0, stream>>>(state, d_out, flag);
}

// Round 5
// 519.987 us; speedup vs baseline: 3.4548x; 1.3590x over previous
//
#include <hip/hip_runtime.h>

typedef unsigned short u16;
typedef unsigned int   u32;

#define NN 16384
#define BN 524288      /* B*N = 32*16384 */
#define LN_EPS 1e-5f

typedef __attribute__((ext_vector_type(8))) short bf16x8;
typedef __attribute__((ext_vector_type(4))) float f32x4;
#define MFMA(a,b,c) __builtin_amdgcn_mfma_f32_16x16x32_bf16(a,b,c,0,0,0)

// ---------------- helpers ----------------
__device__ __forceinline__ float bf2f(u16 h){
  union { u32 u; float f; } c; c.u = ((u32)h) << 16; return c.f;
}
__device__ __forceinline__ u16 f2bf(float f){
  union { float f; u32 u; } c; c.f = f;
  u32 r = (c.u + 0x7fffu + ((c.u >> 16) & 1u)) >> 16;   // RNE
  return (u16)r;
}
__device__ __forceinline__ u32 pack2(float a, float b){
  return (u32)f2bf(a) | ((u32)f2bf(b) << 16);
}
__device__ __forceinline__ void unpack8(uint4 v, float* o){
  o[0]=bf2f((u16)(v.x&0xffffu)); o[1]=bf2f((u16)(v.x>>16));
  o[2]=bf2f((u16)(v.y&0xffffu)); o[3]=bf2f((u16)(v.y>>16));
  o[4]=bf2f((u16)(v.z&0xffffu)); o[5]=bf2f((u16)(v.z>>16));
  o[6]=bf2f((u16)(v.w&0xffffu)); o[7]=bf2f((u16)(v.w>>16));
}
__device__ __forceinline__ float ldin(const void* p, int i, int isbf){
  return isbf ? bf2f(((const u16*)p)[i]) : ((const float*)p)[i];
}

// ---------------- fp32 weight arena offsets (floats) ----------------
enum {
  O_LNING=0, O_LNINB=64, O_LNSG=128, O_LNSB=192, O_LNMG=256, O_LNMB=320,
  O_WQ=384, O_WK=4480, O_WV=8576,
  O_WIH=12672, O_WHH=24960, O_BIH=37248, O_BHH=37440,
  O_MLPW1=37632, O_MLPB1=45824, O_MLPW2=45952, O_MLPB2=54144,
  O_PAW=54208, O_PAB=54336,
  O_PEG=54400, O_PEB=54464, O_PEW1=54528, O_PEB1=62720, O_PEW2=62848, O_PEB2=71040,
  W_TOTAL=71104
};
__device__ const int g_woff[25] = {O_LNING,O_LNINB,O_LNSG,O_LNSB,O_LNMG,O_LNMB,
  O_WQ,O_WK,O_WV,O_WIH,O_WHH,O_BIH,O_BHH,O_MLPW1,O_MLPB1,O_MLPW2,O_MLPB2,
  O_PAW,O_PAB,O_PEG,O_PEB,O_PEW1,O_PEB1,O_PEW2,O_PEB2};
__device__ const int g_wsz[25]  = {64,64,64,64,64,64,4096,4096,4096,12288,12288,
  192,192,8192,128,8192,64,128,64,64,64,8192,128,8192,64};

struct WP { const void* p[25]; };

// ---------------- kernel: detect input dtype ----------------
__global__ void kdetect_kernel(const u16* __restrict__ inp, int* __restrict__ flag){
  if (threadIdx.x == 0 && blockIdx.x == 0){
    int votes = 0;
    for (int i = 0; i < 64; i++){
      u16 h = inp[2*i];
      int e = (h >> 7) & 0xff;
      int m = h & 0x7f;
      if ((e == 0 && m == 0) || (e >= 100 && e <= 144)) votes++;
    }
    flag[0] = (votes >= 48) ? 1 : 0;   // 1 = bf16, 0 = fp32
  }
}

// ---------------- kernel: weight convert (->fp32 arena) + state init ----------------
__global__ __launch_bounds__(256) void kw_kernel(WP wp, float* __restrict__ w,
                                                 float* __restrict__ state,
                                                 const void* __restrict__ slots,
                                                 const int* __restrict__ flag){
  int isbf = flag[0];
  int blk = blockIdx.x;
  if (blk < 25){
    const void* src = wp.p[blk];
    int off = g_woff[blk], sz = g_wsz[blk];
    for (int i = threadIdx.x; i < sz; i += 256)
      w[off + i] = ldin(src, i, isbf);
  } else {
    for (int i = threadIdx.x; i < 512; i += 256){
      float sv = ldin(slots, i, isbf);
      for (int b = 0; b < 32; b++) state[b*512 + i] = sv;
    }
  }
}

// ---------------- kernel: pack B-fragment buffers (bf16, MFMA B-layout) ----------------
__global__ __launch_bounds__(256) void kpack_kernel(WP wp, u16* __restrict__ fkv,
                                                    u16* __restrict__ f1,
                                                    u16* __restrict__ f2,
                                                    const int* __restrict__ flag){
  int isbf = flag[0];
  int blk = blockIdx.x;
  const void* pWk = wp.p[7];  const void* pWv = wp.p[8];
  const void* pW1 = wp.p[21]; const void* pW2 = wp.p[23];
  for (int e = threadIdx.x; e < 8192; e += 256){
    int j = e & 7, lane = (e >> 3) & 63, frag = e >> 9;
    int qd = lane >> 4, l15 = lane & 15;
    if (blk == 0){           // [Wk|Wv]: K=64, N=128, frag = nt*2 + ks
      int nt = frag >> 1, ks = frag & 1;
      int k = ks*32 + qd*8 + j, n = nt*16 + l15;
      float v = (n < 64) ? ldin(pWk, k*64 + n, isbf) : ldin(pWv, k*64 + (n-64), isbf);
      fkv[e] = f2bf(v);
    } else if (blk == 1){    // pe_W1: K=64, N=128
      int nt = frag >> 1, ks = frag & 1;
      int k = ks*32 + qd*8 + j, n = nt*16 + l15;
      f1[e] = f2bf(ldin(pW1, k*128 + n, isbf));
    } else {                 // pe_W2: K=128, N=64, frag = nt*4 + s
      int nt = frag >> 2, s = frag & 3;
      int k = s*32 + qd*8 + j, n = nt*16 + l15;
      f2[e] = f2bf(ldin(pW2, k*64 + n, isbf));
    }
  }
}

// ============== FUSED kernel: LN + [k|v] GEMM + pos-enc MLP (64 rows/block) ==========
// Outputs: kbuf row-major (n x 64), vtg d-major (VT[b][d][n]).
#define KVS 136
__global__ __launch_bounds__(256) void k0_kernel(const void* __restrict__ inpv,
                                                 const float* __restrict__ w,
                                                 const u16* __restrict__ fkv,
                                                 const u16* __restrict__ f1,
                                                 const u16* __restrict__ f2,
                                                 u16* __restrict__ kbuf,
                                                 u16* __restrict__ vtg,
                                                 const int* __restrict__ flag){
  __shared__ __align__(16) u16 shA[5120];     // T1(64x72) -> Hw(4x32x40) -> Vt(64x72)
  __shared__ __align__(16) u16 shB[128*72];   // KV(64xKVS) -> T2(128x72)
  __shared__ float gbuf[128];
  int isbf = flag[0];
  int t = threadIdx.x;
  size_t row0 = (size_t)blockIdx.x * 64;
  int lane = t & 63, wid = t >> 6, qd = lane >> 4, l15 = lane & 15;

  // ---- P1: LN(feats), thread per row (64 rows) ----
  if (t < 64){
    size_t row = row0 + t;
    float x[64], g0, g1;
    if (isbf){
      const u32* up = (const u32*)((const u16*)inpv + row*66);
#pragma unroll
      for (int c = 0; c < 32; c++){
        u32 v = up[c];
        x[2*c] = bf2f((u16)(v & 0xffffu)); x[2*c+1] = bf2f((u16)(v >> 16));
      }
      u32 gv = up[32];
      g0 = bf2f((u16)(gv & 0xffffu)); g1 = bf2f((u16)(gv >> 16));
    } else {
      const float2* fp = (const float2*)((const float*)inpv + row*66);
#pragma unroll
      for (int c = 0; c < 32; c++){ float2 v = fp[c]; x[2*c] = v.x; x[2*c+1] = v.y; }
      float2 gv = fp[32]; g0 = gv.x; g1 = gv.y;
    }
    gbuf[2*t] = g0; gbuf[2*t+1] = g1;
    float mu = 0.f;
#pragma unroll
    for (int i = 0; i < 64; i++) mu += x[i];
    mu *= (1.f/64.f);
    float va = 0.f;
#pragma unroll
    for (int i = 0; i < 64; i++){ x[i] -= mu; va += x[i]*x[i]; }
    va *= (1.f/64.f);
    float rs = rsqrtf(va + LN_EPS);
#pragma unroll
    for (int i = 0; i < 64; i++) x[i] = x[i]*rs*w[O_LNING+i] + w[O_LNINB+i];
#pragma unroll
    for (int c = 0; c < 8; c++){
      uint4 q; q.x = pack2(x[8*c],x[8*c+1]); q.y = pack2(x[8*c+2],x[8*c+3]);
      q.z = pack2(x[8*c+4],x[8*c+5]); q.w = pack2(x[8*c+6],x[8*c+7]);
      *(uint4*)&shA[t*72 + c*8] = q;
    }
  }
  __syncthreads();

  // ---- P2: [k|v] = T1 @ fkv -> KV in shB ----
  {
    bf16x8 af[2];
#pragma unroll
    for (int ks = 0; ks < 2; ks++)
      af[ks] = *(const bf16x8*)&shA[(wid*16 + l15)*72 + ks*32 + qd*8];
#pragma unroll
    for (int nt = 0; nt < 8; nt++){
      bf16x8 b0 = *(const bf16x8*)(fkv + ((size_t)(nt*2+0)*64 + lane)*8);
      bf16x8 b1 = *(const bf16x8*)(fkv + ((size_t)(nt*2+1)*64 + lane)*8);
      f32x4 acc = {0.f,0.f,0.f,0.f};
      acc = MFMA(af[0], b0, acc);
      acc = MFMA(af[1], b1, acc);
      int rb = wid*16 + qd*4;
#pragma unroll
      for (int r = 0; r < 4; r++) shB[(rb+r)*KVS + nt*16 + l15] = f2bf(acc[r]);
    }
  }
  __syncthreads();

  // ---- P3a: pos-enc LN in regs (128 virtual rows: 0-63 k, 64-127 v) ----
  float tv[64];
  int act = (t < 128);
  if (act){
    int phys = t & 63, isv = (t >> 6) & 1;
    float g0 = gbuf[2*phys], g1 = gbuf[2*phys+1];
    const uint4* rp = (const uint4*)&shB[phys*KVS + isv*64];
#pragma unroll
    for (int c = 0; c < 8; c++){ uint4 q4 = rp[c]; unpack8(q4, &tv[c*8]); }
#pragma unroll
    for (int i = 0; i < 64; i++)
      tv[i] += g0*w[O_PAW+i] + g1*w[O_PAW+64+i] + w[O_PAB+i];
    float mu = 0.f;
#pragma unroll
    for (int i = 0; i < 64; i++) mu += tv[i];
    mu *= (1.f/64.f);
    float va = 0.f;
#pragma unroll
    for (int i = 0; i < 64; i++){ tv[i] -= mu; va += tv[i]*tv[i]; }
    va *= (1.f/64.f);
    float rs = rsqrtf(va + LN_EPS);
#pragma unroll
    for (int i = 0; i < 64; i++) tv[i] = tv[i]*rs*w[O_PEG+i] + w[O_PEB+i];
  }
  __syncthreads();         // KV reads done; shB reusable
  if (act){
#pragma unroll
    for (int c = 0; c < 8; c++){
      uint4 q; q.x = pack2(tv[8*c],tv[8*c+1]); q.y = pack2(tv[8*c+2],tv[8*c+3]);
      q.z = pack2(tv[8*c+4],tv[8*c+5]); q.w = pack2(tv[8*c+6],tv[8*c+7]);
      *(uint4*)&shB[t*72 + c*8] = q;
    }
  }
  __syncthreads();

  // ---- P4: MLP; wave covers 32 virtual rows ----
  f32x4 out[2][4];
  {
    u16* Hw = shA + wid*1280;                  // 32 rows x 40 u16
    bf16x8 af[2][2];
#pragma unroll
    for (int mt = 0; mt < 2; mt++)
#pragma unroll
      for (int ks = 0; ks < 2; ks++)
        af[mt][ks] = *(const bf16x8*)&shB[(wid*32 + mt*16 + l15)*72 + ks*32 + qd*8];
#pragma unroll
    for (int mt = 0; mt < 2; mt++)
#pragma unroll
      for (int nt = 0; nt < 4; nt++) out[mt][nt] = (f32x4){0.f,0.f,0.f,0.f};

#pragma unroll
    for (int s = 0; s < 4; s++){
#pragma unroll
      for (int e = 0; e < 2; e++){
        int nn = s*2 + e;
        bf16x8 b0 = *(const bf16x8*)(f1 + ((size_t)(nn*2+0)*64 + lane)*8);
        bf16x8 b1 = *(const bf16x8*)(f1 + ((size_t)(nn*2+1)*64 + lane)*8);
        float bias1 = w[O_PEB1 + nn*16 + l15];
#pragma unroll
        for (int mt = 0; mt < 2; mt++){
          f32x4 h = {0.f,0.f,0.f,0.f};
          h = MFMA(af[mt][0], b0, h);
          h = MFMA(af[mt][1], b1, h);
#pragma unroll
          for (int r = 0; r < 4; r++)
            Hw[(mt*16 + qd*4 + r)*40 + e*16 + l15] = f2bf(fmaxf(h[r] + bias1, 0.f));
        }
      }
      bf16x8 a2[2];
#pragma unroll
      for (int mt = 0; mt < 2; mt++)
        a2[mt] = *(const bf16x8*)&Hw[(mt*16 + l15)*40 + qd*8];   // same-wave RAW
#pragma unroll
      for (int nt = 0; nt < 4; nt++){
        bf16x8 bw = *(const bf16x8*)(f2 + ((size_t)(nt*4 + s)*64 + lane)*8);
#pragma unroll
        for (int mt = 0; mt < 2; mt++)
          out[mt][nt] = MFMA(a2[mt], bw, out[mt][nt]);
      }
    }
  }
  __syncthreads();   // all Hw reads done; shA reusable as Vt

  // ---- epilogue: k rows -> global row-major; v rows -> Vt LDS transpose ----
  if (wid < 2){
#pragma unroll
    for (int nt = 0; nt < 4; nt++){
      float b2v = w[O_PEB2 + nt*16 + l15];
#pragma unroll
      for (int mt = 0; mt < 2; mt++){
        size_t rb = row0 + wid*32 + mt*16 + qd*4;
#pragma unroll
        for (int r = 0; r < 4; r++)
          kbuf[(rb+r)*64 + nt*16 + l15] = f2bf(out[mt][nt][r] + b2v);
      }
    }
  } else {
#pragma unroll
    for (int nt = 0; nt < 4; nt++){
      float b2v = w[O_PEB2 + nt*16 + l15];
#pragma unroll
      for (int mt = 0; mt < 2; mt++){
        int vr = (wid-2)*32 + mt*16 + qd*4;
#pragma unroll
        for (int r = 0; r < 4; r++)
          shA[(nt*16 + l15)*72 + vr + r] = f2bf(out[mt][nt][r] + b2v);
      }
    }
  }
  __syncthreads();

  // ---- copy Vt -> vtg [b][d][n] ----
  {
    int d = t >> 2, c = t & 3;
    int b  = (int)(row0 >> 14);
    int nl = (int)(row0 & 16383);
    uint4 v0 = *(const uint4*)&shA[d*72 + c*16];
    uint4 v1 = *(const uint4*)&shA[d*72 + c*16 + 8];
    u16* dst = vtg + (size_t)b*1048576 + (size_t)d*NN + nl + c*16;
    *(uint4*)dst = v0;
    *(uint4*)(dst + 8) = v1;
  }
}

// ---------------- kernel: q = LN(state)@Wq -> qf (MFMA B-frag, bf16) -------------
__global__ __launch_bounds__(512) void b1_kernel(const float* __restrict__ w,
                                                 const float* __restrict__ state,
                                                 u16* __restrict__ qf){
  __shared__ float qrow[8*64];
  int b = blockIdx.x, t = threadIdx.x;
  int s = t >> 6, lane = t & 63;
  float xv = state[(b*8+s)*64 + lane];
  float sum = xv;
#pragma unroll
  for (int off = 32; off; off >>= 1) sum += __shfl_xor(sum, off, 64);
  float mu = sum * (1.f/64.f);
  float xc = xv - mu;
  float ss = xc*xc;
#pragma unroll
  for (int off = 32; off; off >>= 1) ss += __shfl_xor(ss, off, 64);
  float rs = rsqrtf(ss*(1.f/64.f) + LN_EPS);
  float xln = xc*rs*w[O_LNSG+lane] + w[O_LNSB+lane];
  float acc = 0.f;
#pragma unroll
  for (int i = 0; i < 64; i++){
    float xi = __shfl(xln, i, 64);
    acc += xi * w[O_WQ + i*64 + lane];
  }
  qrow[s*64 + lane] = acc;
  __syncthreads();
  if (t < 128){
    int ks = t >> 6, ln = t & 63, ql = ln & 15, qq = ln >> 4;
    u32 pk[4];
#pragma unroll
    for (int jp = 0; jp < 4; jp++){
      float v0 = (ql < 8) ? qrow[ql*64 + ks*32 + qq*8 + 2*jp]     : 0.f;
      float v1 = (ql < 8) ? qrow[ql*64 + ks*32 + qq*8 + 2*jp + 1] : 0.f;
      pk[jp] = pack2(v0, v1);
    }
    *(uint4*)(qf + ((size_t)(b*2+ks)*64 + ln)*8) = *(uint4*)pk;
  }
}

// ---------------- kernel: attention (MFMA QK + softmax + MFMA PV), 512 n/block ----
__global__ __launch_bounds__(256) void b2_kernel(const u16* __restrict__ kbuf,
                                                 const u16* __restrict__ vtg,
                                                 const u16* __restrict__ qf,
                                                 float* __restrict__ pupd,
                                                 float* __restrict__ psums){
  __shared__ __align__(16) u16 pm[16*512];       // P, bf16, chunk-XOR swizzled
  int t = threadIdx.x, lane = t & 63, wid = t >> 6, l15 = lane & 15, quad = lane >> 4;
  int b = blockIdx.x >> 5, chunk = blockIdx.x & 31;
  size_t gn0 = (size_t)b*NN + (size_t)chunk*512;

  for (int i = t; i < 4096; i += 256) pm[4096 + i] = 0;   // zero slot rows 8..15

  bf16x8 q0 = *(const bf16x8*)(qf + ((size_t)(b*2+0)*64 + lane)*8);
  bf16x8 q1 = *(const bf16x8*)(qf + ((size_t)(b*2+1)*64 + lane)*8);

  float psum = 0.f;
  int wbase = wid*128;
#pragma unroll
  for (int mt = 0; mt < 8; mt++){
    const u16* kp = kbuf + (gn0 + wbase + mt*16 + l15)*64;
    bf16x8 a0 = *(const bf16x8*)(kp + quad*8);
    bf16x8 a1 = *(const bf16x8*)(kp + 32 + quad*8);
    f32x4 dg = {0.f,0.f,0.f,0.f};
    dg = MFMA(a0, q0, dg);
    dg = MFMA(a1, q1, dg);
#pragma unroll
    for (int r = 0; r < 4; r++){
      float lg = dg[r]*0.125f;
      float mx = lg;
      mx = fmaxf(mx, __shfl_xor(mx, 1, 64));
      mx = fmaxf(mx, __shfl_xor(mx, 2, 64));
      mx = fmaxf(mx, __shfl_xor(mx, 4, 64));
      float ex = __expf(lg - mx);
      float es = ex;
      es += __shfl_xor(es, 1, 64);
      es += __shfl_xor(es, 2, 64);
      es += __shfl_xor(es, 4, 64);
      float p = ex/es + 1e-8f;
      psum += p;
      if (l15 < 8){
        int n = wbase + mt*16 + quad*4 + r;
        pm[l15*512 + (((n>>3) ^ l15) << 3) + (n & 7)] = f2bf(p);
      }
    }
  }
  psum += __shfl_xor(psum, 16, 64);
  psum += __shfl_xor(psum, 32, 64);
  if (quad == 0 && l15 < 8)
    psums[(size_t)((b*32+chunk)*4 + wid)*8 + l15] = psum;
  __syncthreads();

  // PV: D[s][d] ; wave wid handles d-tile wid*16..+15 over full 512-k
  f32x4 acc = {0.f,0.f,0.f,0.f};
  const u16* vp = vtg + (size_t)b*1048576 + (size_t)(wid*16 + l15)*NN
                      + (size_t)chunk*512 + quad*8;
  const u16* pmr = pm + l15*512;
#pragma unroll
  for (int ks = 0; ks < 16; ks++){
    int kc = ks*4 + quad;
    bf16x8 pa = *(const bf16x8*)(pmr + ((kc ^ l15) << 3));
    bf16x8 vb = *(const bf16x8*)(vp + ks*32);
    acc = MFMA(pa, vb, acc);
  }
  if (quad < 2){
    float* ob = pupd + (size_t)(b*32+chunk)*512 + (size_t)(quad*4)*64 + wid*16 + l15;
#pragma unroll
    for (int r = 0; r < 4; r++) ob[(size_t)r*64] = acc[r];
  }
}

// ---------------- kernel: partial-reduce + GRU + MLP, one block per (b,s) --------
__global__ __launch_bounds__(192) void b3_kernel(const float* __restrict__ w,
                                                 float* __restrict__ state,
                                                 const float* __restrict__ pupd,
                                                 const float* __restrict__ psums){
  __shared__ float uL[64], pv[64], hL[64], hln[64], gx[192], gh[192], hid[128], red[128];
  __shared__ float ssum;
  int bs = blockIdx.x, b = bs >> 3, s = bs & 7, t = threadIdx.x;

  if (t < 64){
    float a = 0.f;
    const float* pp = pupd + (size_t)b*32*512 + s*64 + t;
#pragma unroll 4
    for (int c = 0; c < 32; c++) a += pp[(size_t)c*512];
    uL[t] = a;
    pv[t] = state[(b*8+s)*64 + t];
  } else {
    int i = t - 64;    // 128 (chunk,wave) partial sums
    red[i] = psums[(size_t)(b*128 + i)*8 + s];
  }
  __syncthreads();
  if (t == 0){ float a = 0.f; for (int i = 0; i < 128; i++) a += red[i]; ssum = a; }
  __syncthreads();

  { // gx, gh (j = t, 192 threads)
    float inv = 1.f/ssum;
    int j = t;
    float x0=0.f,x1=0.f,x2=0.f,x3=0.f, y0=0.f,y1=0.f,y2=0.f,y3=0.f;
#pragma unroll 4
    for (int d = 0; d < 64; d += 4){
      x0 += uL[d]  *w[O_WIH + (d)*192 + j];   y0 += pv[d]  *w[O_WHH + (d)*192 + j];
      x1 += uL[d+1]*w[O_WIH + (d+1)*192 + j]; y1 += pv[d+1]*w[O_WHH + (d+1)*192 + j];
      x2 += uL[d+2]*w[O_WIH + (d+2)*192 + j]; y2 += pv[d+2]*w[O_WHH + (d+2)*192 + j];
      x3 += uL[d+3]*w[O_WIH + (d+3)*192 + j]; y3 += pv[d+3]*w[O_WHH + (d+3)*192 + j];
    }
    gx[j] = w[O_BIH + j] + (x0+x1+x2+x3)*inv;
    gh[j] = w[O_BHH + j] + (y0+y1+y2+y3);
  }
  __syncthreads();

  if (t < 64){
    int d = t;
    float r = 1.f/(1.f + expf(-(gx[d]      + gh[d])));
    float z = 1.f/(1.f + expf(-(gx[64+d]   + gh[64+d])));
    float nv = tanhf(gx[128+d] + r*gh[128+d]);
    hL[d] = (1.f - z)*nv + z*pv[d];
  }
  __syncthreads();

  if (t < 64){
    float h = hL[t];
    float sum = h;
#pragma unroll
    for (int off = 32; off; off >>= 1) sum += __shfl_xor(sum, off, 64);
    float mu = sum * (1.f/64.f);
    float xc = h - mu;
    float ss2 = xc*xc;
#pragma unroll
    for (int off = 32; off; off >>= 1) ss2 += __shfl_xor(ss2, off, 64);
    float rs = rsqrtf(ss2*(1.f/64.f) + LN_EPS);
    hln[t] = xc*rs*w[O_LNMG+t] + w[O_LNMB+t];
  }
  __syncthreads();

  if (t < 128){
    int j = t;
    float a0=0.f,a1=0.f,a2v=0.f,a3=0.f;
#pragma unroll 4
    for (int d = 0; d < 64; d += 4){
      a0  += hln[d]  *w[O_MLPW1 + (d)*128 + j];
      a1  += hln[d+1]*w[O_MLPW1 + (d+1)*128 + j];
      a2v += hln[d+2]*w[O_MLPW1 + (d+2)*128 + j];
      a3  += hln[d+3]*w[O_MLPW1 + (d+3)*128 + j];
    }
    hid[j] = fmaxf(a0+a1+a2v+a3 + w[O_MLPB1 + j], 0.f);
  }
  __syncthreads();

  if (t < 64){
    int d = t;
    float o0=0.f,o1=0.f,o2=0.f,o3=0.f;
#pragma unroll 4
    for (int j = 0; j < 128; j += 4){
      o0 += hid[j]  *w[O_MLPW2 + (j)*64 + d];
      o1 += hid[j+1]*w[O_MLPW2 + (j+1)*64 + d];
      o2 += hid[j+2]*w[O_MLPW2 + (j+2)*64 + d];
      o3 += hid[j+3]*w[O_MLPW2 + (j+3)*64 + d];
    }
    state[(b*8+s)*64 + d] = hL[d] + o0+o1+o2+o3 + w[O_MLPB2 + d];
  }
}

// ---------------- kernel: state (fp32) -> out (bf16 or fp32 per flag) ----------------
__global__ __launch_bounds__(256) void kout_kernel(const float* __restrict__ state,
                                                   void* __restrict__ out,
                                                   const int* __restrict__ flag){
  int i = blockIdx.x*256 + threadIdx.x;
  if (flag[0]) ((u16*)out)[i] = f2bf(state[i]);
  else         ((float*)out)[i] = state[i];
}

// ---------------- launch ----------------
extern "C" void kernel_launch(void* const* d_in, const int* in_sizes, int n_in,
                              void* d_out, int out_size, void* d_ws, size_t ws_size,
                              hipStream_t stream){
  const void* inp   = d_in[0];
  const void* slots = d_in[1];
  WP wp;
  for (int i = 0; i < 25; i++) wp.p[i] = d_in[2+i];

  u16*   kbuf  = (u16*)d_ws;                         // BN*64 bf16 (k_pos, row-major)
  u16*   vtg   = kbuf + (size_t)BN*64;               // BN*64 bf16 (v_pos, d-major [b][d][n])
  float* w     = (float*)(vtg + (size_t)BN*64);      // fp32 weight arena
  float* state = w + W_TOTAL;                        // 32*8*64
  float* pupd  = state + 16384;                      // 32*32*512 partials
  float* psums = pupd + 524288;                      // 32*32*4*8
  u16*   qf    = (u16*)(psums + 32768);              // 32*2*64*8 bf16 B-frags
  u16*   fkv   = qf + 32768;
  u16*   f1    = fkv + 8192;
  u16*   f2    = f1 + 8192;
  int*   flag  = (int*)(f2 + 8192);

  kdetect_kernel<<<1, 64, 0, stream>>>((const u16*)inp, flag);
  kw_kernel<<<26, 256, 0, stream>>>(wp, w, state, slots, flag);
  kpack_kernel<<<3, 256, 0, stream>>>(wp, fkv, f1, f2, flag);
  k0_kernel<<<8192, 256, 0, stream>>>(inp, w, fkv, f1, f2, kbuf, vtg, flag);
  for (int it = 0; it < 3; it++){
    b1_kernel<<<32, 512, 0, stream>>>(w, state, qf);
    b2_kernel<<<1024, 256, 0, stream>>>(kbuf, vtg, qf, pupd, psums);
    b3_kernel<<<256, 192, 0, stream>>>(w, state, pupd, psums);
  }
  kout_kernel<<<64, 256, 0, stream>>>(state, d_out, flag);
}